// Round 3
// baseline (411.344 us; speedup 1.0000x reference)
//
#include <hip/hip_runtime.h>

#define N_NODES 8192
#define FDIM 128
#define NEG_SLOPE 0.2f
#define SEG 512   // per-wave neighbor capacity (mean ~102, huge headroom)
#define RPB 16    // rows per block in wh_fused (76 KB LDS -> 2 blocks/CU)

// float -> bf16 bits, round-to-nearest-even (values are all normal finite)
__device__ __forceinline__ unsigned int f2bf(float f) {
  unsigned int u = __float_as_uint(f);
  return (u + 0x7FFFu + ((u >> 16) & 1u)) >> 16;
}

// ---------------- Kernel A: Whb(bf16) = h @ W.T, colsum S, s1/s2 scores ----
// 16 rows/block => LDS 76 KB => 2 blocks/CU (2 waves/SIMD) for latency hiding;
// the previous 32-row version ran at 1 wave/SIMD with zero TLP.
__global__ __launch_bounds__(256) void wh_fused_kernel(
    const float* __restrict__ h, const float* __restrict__ W,
    const float* __restrict__ a,
    unsigned int* __restrict__ Whb,   // packed bf16x2: N rows x 64 uints
    float* __restrict__ s1, float* __restrict__ s2,
    float* __restrict__ S) {
  __shared__ float Wt[FDIM * 132];   // Wt[k*132+o] = W[o][k]  (67.6 KB)
  __shared__ float rows[RPB * 132];  // rows[r*132+k]; reused as colsum scratch
  const int t = threadIdx.x;
  const int base = blockIdx.x * RPB;
  // stage W^T via float4 loads (4096 float4 / 256 thr = 16 iters)
  for (int it = 0; it < 16; ++it) {
    int idx = t + 256 * it;          // float4 index into W
    int o = idx >> 5, c = (idx & 31) * 4;
    float4 w4 = *(const float4*)&W[o * FDIM + c];
    Wt[(c + 0) * 132 + o] = w4.x;
    Wt[(c + 1) * 132 + o] = w4.y;
    Wt[(c + 2) * 132 + o] = w4.z;
    Wt[(c + 3) * 132 + o] = w4.w;
  }
  // stage h rows via float4 (512 float4 / 256 thr = 2 iters)
  for (int it = 0; it < 2; ++it) {
    int idx = t + 256 * it;
    int r = idx >> 5, c = (idx & 31) * 4;
    *(float4*)&rows[r * 132 + c] =
        *(const float4*)&h[(size_t)(base + r) * FDIM + c];
  }
  __syncthreads();
  const int c4 = (t & 31) * 4;
  const int g = t >> 5;              // 0..7 ; this thread-group owns rows 2g,2g+1
  float acc[2][4];
#pragma unroll
  for (int rr = 0; rr < 2; ++rr)
#pragma unroll
    for (int cc = 0; cc < 4; ++cc) acc[rr][cc] = 0.f;
  for (int k = 0; k < FDIM; ++k) {
    float4 wv = *(const float4*)&Wt[k * 132 + c4];
    float r0 = rows[(2 * g + 0) * 132 + k];
    float r1 = rows[(2 * g + 1) * 132 + k];
    acc[0][0] += r0 * wv.x; acc[0][1] += r0 * wv.y;
    acc[0][2] += r0 * wv.z; acc[0][3] += r0 * wv.w;
    acc[1][0] += r1 * wv.x; acc[1][1] += r1 * wv.y;
    acc[1][2] += r1 * wv.z; acc[1][3] += r1 * wv.w;
  }
  // ---- bf16 store of Wh (gather operand; 2 MB total -> L2-resident) ----
#pragma unroll
  for (int rr = 0; rr < 2; ++rr) {
    int r = base + 2 * g + rr;
    unsigned int p0 = f2bf(acc[rr][0]) | (f2bf(acc[rr][1]) << 16);
    unsigned int p1 = f2bf(acc[rr][2]) | (f2bf(acc[rr][3]) << 16);
    *(uint2*)&Whb[(size_t)r * 64 + (c4 >> 1)] = make_uint2(p0, p1);
  }
  // ---- fused scores: s1 = Wh@a1, s2 = Wh@a2 (32-lane shfl tree) ----
  {
    float4 a1v = *(const float4*)&a[c4];
    float4 a2v = *(const float4*)&a[FDIM + c4];
#pragma unroll
    for (int rr = 0; rr < 2; ++rr) {
      float d1 = acc[rr][0] * a1v.x + acc[rr][1] * a1v.y +
                 acc[rr][2] * a1v.z + acc[rr][3] * a1v.w;
      float d2 = acc[rr][0] * a2v.x + acc[rr][1] * a2v.y +
                 acc[rr][2] * a2v.z + acc[rr][3] * a2v.w;
#pragma unroll
      for (int off = 16; off; off >>= 1) {
        d1 += __shfl_down(d1, off);
        d2 += __shfl_down(d2, off);
      }
      if ((t & 31) == 0) {
        s1[base + 2 * g + rr] = d1;
        s2[base + 2 * g + rr] = d2;
      }
    }
  }
  __syncthreads();
  float4 cs = make_float4(acc[0][0] + acc[1][0], acc[0][1] + acc[1][1],
                          acc[0][2] + acc[1][2], acc[0][3] + acc[1][3]);
  *(float4*)&rows[g * FDIM + c4] = cs;
  __syncthreads();
  if (t < FDIM) {
    float s = 0.f;
#pragma unroll
    for (int gg = 0; gg < 8; ++gg) s += rows[gg * FDIM + t];
    atomicAdd(&S[t], s);
  }
}

// non-temporal float4 load: adj is streamed exactly once — keep it out of
// the L2 working set so Whb (2 MB) stays resident for the gather phase.
__device__ __forceinline__ float4 ntload4(const float4* p) {
  typedef float f4v __attribute__((ext_vector_type(4)));
  f4v v = __builtin_nontemporal_load((const f4v*)p);
  return make_float4(v[0], v[1], v[2], v[3]);
}

// exact wave64 prefix-popcount of ballot mask below this lane (2 VALU ops)
__device__ __forceinline__ int mbcnt64(unsigned long long b) {
  return (int)__builtin_amdgcn_mbcnt_hi(
      (unsigned)(b >> 32), __builtin_amdgcn_mbcnt_lo((unsigned)b, 0u));
}

// ---------------- Kernel B: per-row softmax + sparse gather ----------------
// one block (4 waves) per row i.
// scan:   adj ONLY. 8 float4 loads issued upfront, then processed chunk-by-
//         chunk so the compiler emits INCREMENTAL vmcnt(7..0) waits — ballot
//         VALU for chunk c overlaps the in-flight loads of chunks c+1..7.
//         (round-1's asm keep-alive + sched_barrier forced a full vmcnt(0)
//         drain before any compute: the CU alternated mem-burst / compute
//         windows, which is exactly the VALUBusy 32% + HBM 30% signature.)
// phase2: e = leakyrelu(s1i + s2[j]) via random 4B gathers, wave max.
// phase3: p = exp(e-m) once per pair, wave sum.
// gather: half-wave per pair, bf16 rows (256 B each, 8 B/lane), 4-deep unroll.
__global__ __launch_bounds__(256, 4) void gat_row_kernel(
    const float* __restrict__ adj, const unsigned int* __restrict__ Whb,
    const float* __restrict__ s1, const float* __restrict__ s2,
    const float* __restrict__ S, float* __restrict__ out) {
  const int i = blockIdx.x;
  const int t = threadIdx.x;
  const int lane = t & 63;
  const int wave = t >> 6;
  __shared__ float2 pairs[4 * SEG];  // .x = e then p ; .y = j (int bits)
  __shared__ int counts[4];
  __shared__ float red[4];           // per-wave max
  __shared__ float red2[4];          // per-wave exp-sum
  __shared__ float fpart[4][FDIM];

  const float s1i = s1[i];
  const float4* __restrict__ arow = (const float4*)(adj + (size_t)i * N_NODES);
  float2* __restrict__ mypairs = pairs + wave * SEG;

  // ---- scan: 8 chunks in flight, incremental waits, ballot compaction ----
  float4 av[8];
#pragma unroll
  for (int it = 0; it < 8; ++it) av[it] = ntload4(&arow[it * 256 + t]);
  int cbase = 0;
#pragma unroll
  for (int it = 0; it < 8; ++it) {
    const int j4 = it * 256 + t;
    float v[4] = {av[it].x, av[it].y, av[it].z, av[it].w};
#pragma unroll
    for (int c = 0; c < 4; ++c) {
      bool pred = (v[c] != 0.f);
      unsigned long long b = __ballot(pred);
      if (pred) {
        int pos = cbase + mbcnt64(b);
        if (pos < SEG) ((int*)&mypairs[pos])[1] = j4 * 4 + c;
      }
      cbase += (int)__popcll(b);
    }
  }
  const int mycnt = cbase < SEG ? cbase : SEG;
  if (lane == 0) counts[wave] = mycnt;

  // ---- phase2: e from s2[j] gathers, wave max ----
  float lmax = -1e30f;
  for (int k = lane; k < mycnt; k += 64) {
    int j = ((const int*)&mypairs[k])[1];
    float e = s1i + s2[j];
    e = e > 0.f ? e : NEG_SLOPE * e;
    mypairs[k].x = e;
    lmax = fmaxf(lmax, e);
  }
  for (int off = 32; off; off >>= 1) lmax = fmaxf(lmax, __shfl_down(lmax, off));
  if (lane == 0) red[wave] = lmax;
  __syncthreads();
  const int cnt = counts[0] + counts[1] + counts[2] + counts[3];
  float m = fmaxf(fmaxf(red[0], red[1]), fmaxf(red[2], red[3]));
  if (cnt < N_NODES) m = fmaxf(m, 0.f);  // adj==0 entries contribute z=0
  const float em = __expf(-m);

  // ---- phase3: p = exp(e-m) once per pair, wave sum ----
  float lsum = 0.f;
  for (int k = lane; k < mycnt; k += 64) {
    float p = __expf(mypairs[k].x - m);
    mypairs[k].x = p;
    lsum += p;
  }
  for (int off = 32; off; off >>= 1) lsum += __shfl_down(lsum, off);
  if (lane == 0) red2[wave] = lsum;
  // no barrier needed: gather below reads only this wave's own segment

  // ---- gather: half-wave per pair, bf16 rows, 4-deep unroll ----
  const int half = lane >> 5, lq = lane & 31;
  const uint2* __restrict__ Whb2 = (const uint2*)Whb;  // 32 x uint2 per row
  float ax = 0.f, ay = 0.f, az = 0.f, aw = 0.f;
  const int nit = (mycnt + 1) >> 1;
  int it = 0;
  for (; it + 3 < nit; it += 4) {
#pragma unroll
    for (int c = 0; c < 4; ++c) {
      int p = 2 * (it + c) + half;
      bool ok = p < mycnt;
      float2 pr = mypairs[ok ? p : 0];
      int j = ((const int*)&pr)[1];
      uint2 d = Whb2[((size_t)j << 5) + lq];
      float w = ok ? pr.x - em : 0.f;
      ax += w * __uint_as_float(d.x << 16);
      ay += w * __uint_as_float(d.x & 0xffff0000u);
      az += w * __uint_as_float(d.y << 16);
      aw += w * __uint_as_float(d.y & 0xffff0000u);
    }
  }
  for (; it < nit; ++it) {
    int p = 2 * it + half;
    bool ok = p < mycnt;
    float2 pr = mypairs[ok ? p : 0];
    int j = ((const int*)&pr)[1];
    uint2 d = Whb2[((size_t)j << 5) + lq];
    float w = ok ? pr.x - em : 0.f;
    ax += w * __uint_as_float(d.x << 16);
    ay += w * __uint_as_float(d.x & 0xffff0000u);
    az += w * __uint_as_float(d.y << 16);
    aw += w * __uint_as_float(d.y & 0xffff0000u);
  }
  // combine odd/even halves (same features, disjoint neighbor subsets)
  ax += __shfl_down(ax, 32);
  ay += __shfl_down(ay, 32);
  az += __shfl_down(az, 32);
  aw += __shfl_down(aw, 32);
  if (lane < 32)
    *(float4*)&fpart[wave][4 * lq] = make_float4(ax, ay, az, aw);
  __syncthreads();
  if (t < FDIM) {
    float l = red2[0] + red2[1] + red2[2] + red2[3]
              + (float)(N_NODES - cnt) * em;
    float o = (fpart[0][t] + fpart[1][t] + fpart[2][t] + fpart[3][t]
               + em * S[t]) / l;
    out[(size_t)i * FDIM + t] = o;
  }
}

extern "C" void kernel_launch(void* const* d_in, const int* in_sizes, int n_in,
                              void* d_out, int out_size, void* d_ws, size_t ws_size,
                              hipStream_t stream) {
  const float* h   = (const float*)d_in[0];
  const float* adj = (const float*)d_in[1];
  const float* W   = (const float*)d_in[2];
  const float* a   = (const float*)d_in[3];
  float* out = (float*)d_out;
  // workspace layout: Whb(bf16, N*64 uints = 2 MB) | s1[N] | s2[N] | S[F]
  unsigned int* Whb = (unsigned int*)d_ws;
  float* s1 = (float*)(Whb + (size_t)N_NODES * 64);
  float* s2 = s1 + N_NODES;
  float* S  = s2 + N_NODES;

  hipMemsetAsync(S, 0, FDIM * sizeof(float), stream);
  hipLaunchKernelGGL(wh_fused_kernel, dim3(N_NODES / RPB), dim3(256), 0, stream,
                     h, W, a, Whb, s1, s2, S);
  hipLaunchKernelGGL(gat_row_kernel, dim3(N_NODES), dim3(256), 0, stream,
                     adj, Whb, s1, s2, S, out);
}

// Round 4
// 410.230 us; speedup vs baseline: 1.0027x; 1.0027x over previous
//
#include <hip/hip_runtime.h>

#define N_NODES 8192
#define FDIM 128
#define NEG_SLOPE 0.2f
#define SEG 512   // per-wave neighbor capacity (mean ~102, 5 sigma headroom)

// float -> bf16 bits, round-to-nearest-even (values are all normal finite)
__device__ __forceinline__ unsigned int f2bf(float f) {
  unsigned int u = __float_as_uint(f);
  return (u + 0x7FFFu + ((u >> 16) & 1u)) >> 16;
}

// ---------------- Kernel 0: WtG = W^T (one-time, 64 KB) -------------------
// lets wh_fused stage W^T with coalesced float4 loads + conflict-free b128
// LDS stores (the old in-kernel transposed scatter was a 16-way bank
// conflict: 4-aligned LDS strides always land 32 lanes on <=2 banks).
__global__ __launch_bounds__(256) void transpose_w_kernel(
    const float* __restrict__ W, float* __restrict__ WtG) {
  int idx = blockIdx.x * 256 + threadIdx.x;   // idx = k*128+o of WtG
  WtG[idx] = W[(idx & 127) * FDIM + (idx >> 7)];  // strided read, coalesced write
}

// ---------------- Kernel A: Whb(bf16) = h @ W.T, colsum S, s1/s2 scores ----
__global__ __launch_bounds__(256) void wh_fused_kernel(
    const float* __restrict__ h, const float* __restrict__ WtG,
    const float* __restrict__ a,
    unsigned int* __restrict__ Whb,   // packed bf16x2: N rows x 64 uints
    float* __restrict__ s1, float* __restrict__ s2,
    float* __restrict__ S) {
  __shared__ float Wt[FDIM * 132];   // Wt[k*132+o] (67.6 KB)
  __shared__ float rows[32 * 132];   // rows[r*132+k]; reused as colsum scratch
  const int t = threadIdx.x;
  const int base = blockIdx.x * 32;
  // stage W^T: float4 loads -> b128 LDS stores, conflict-free
  for (int it = 0; it < 16; ++it) {
    int idx = t + 256 * it;          // float4 index into WtG
    int k = idx >> 5, c = (idx & 31) * 4;
    *(float4*)&Wt[k * 132 + c] = *(const float4*)&WtG[k * FDIM + c];
  }
  // stage 32 h rows: float4, conflict-free
  for (int it = 0; it < 4; ++it) {
    int idx = t + 256 * it;
    int r = idx >> 5, c = (idx & 31) * 4;
    *(float4*)&rows[r * 132 + c] =
        *(const float4*)&h[(size_t)(base + r) * FDIM + c];
  }
  __syncthreads();
  const int c4 = (t & 31) * 4;
  const int g = t >> 5;              // 8 groups x 4 rows
  float acc[4][4];
#pragma unroll
  for (int rr = 0; rr < 4; ++rr)
#pragma unroll
    for (int cc = 0; cc < 4; ++cc) acc[rr][cc] = 0.f;
  for (int k = 0; k < FDIM; ++k) {
    float4 wv = *(const float4*)&Wt[k * 132 + c4];   // b128, conflict-free
    float rv[4];
#pragma unroll
    for (int rr = 0; rr < 4; ++rr) rv[rr] = rows[(4 * g + rr) * 132 + k];  // broadcast
#pragma unroll
    for (int rr = 0; rr < 4; ++rr) {
      acc[rr][0] += rv[rr] * wv.x;
      acc[rr][1] += rv[rr] * wv.y;
      acc[rr][2] += rv[rr] * wv.z;
      acc[rr][3] += rv[rr] * wv.w;
    }
  }
  // bf16 store of Wh (gather operand; 2 MB total -> L2-resident)
#pragma unroll
  for (int rr = 0; rr < 4; ++rr) {
    int r = base + 4 * g + rr;
    unsigned int p0 = f2bf(acc[rr][0]) | (f2bf(acc[rr][1]) << 16);
    unsigned int p1 = f2bf(acc[rr][2]) | (f2bf(acc[rr][3]) << 16);
    *(uint2*)&Whb[(size_t)r * 64 + (c4 >> 1)] = make_uint2(p0, p1);
  }
  // fused scores: s1 = Wh@a1, s2 = Wh@a2 (32-lane shfl tree)
  {
    float4 a1v = *(const float4*)&a[c4];
    float4 a2v = *(const float4*)&a[FDIM + c4];
#pragma unroll
    for (int rr = 0; rr < 4; ++rr) {
      float d1 = acc[rr][0] * a1v.x + acc[rr][1] * a1v.y +
                 acc[rr][2] * a1v.z + acc[rr][3] * a1v.w;
      float d2 = acc[rr][0] * a2v.x + acc[rr][1] * a2v.y +
                 acc[rr][2] * a2v.z + acc[rr][3] * a2v.w;
#pragma unroll
      for (int off = 16; off; off >>= 1) {
        d1 += __shfl_down(d1, off);
        d2 += __shfl_down(d2, off);
      }
      if ((t & 31) == 0) {
        s1[base + 4 * g + rr] = d1;
        s2[base + 4 * g + rr] = d2;
      }
    }
  }
  __syncthreads();
  float4 cs = make_float4(acc[0][0] + acc[1][0] + acc[2][0] + acc[3][0],
                          acc[0][1] + acc[1][1] + acc[2][1] + acc[3][1],
                          acc[0][2] + acc[1][2] + acc[2][2] + acc[3][2],
                          acc[0][3] + acc[1][3] + acc[2][3] + acc[3][3]);
  *(float4*)&rows[g * FDIM + c4] = cs;
  __syncthreads();
  if (t < FDIM) {
    float s = 0.f;
#pragma unroll
    for (int gg = 0; gg < 8; ++gg) s += rows[gg * FDIM + t];
    atomicAdd(&S[t], s);
  }
}

// non-temporal float4 load: adj is streamed exactly once — keep it out of
// the L2 working set so Whb (2 MB) + s2 stay resident.
__device__ __forceinline__ float4 ntload4(const float4* p) {
  typedef float f4v __attribute__((ext_vector_type(4)));
  f4v v = __builtin_nontemporal_load((const f4v*)p);
  return make_float4(v[0], v[1], v[2], v[3]);
}

// exact wave64 prefix-popcount of ballot mask below this lane (2 VALU ops)
__device__ __forceinline__ int mbcnt64(unsigned long long b) {
  return (int)__builtin_amdgcn_mbcnt_hi(
      (unsigned)(b >> 32), __builtin_amdgcn_mbcnt_lo((unsigned)b, 0u));
}

// ---------------- Kernel B: per-row softmax + sparse gather ----------------
// one block (4 waves) per row i. TWO-phase structure (was 4):
// scan:   adj chunks (ntload4) + s2 chunks (COALESCED float4 — s2 for adj
//         chunk `it` is exactly s2[it*1024+4t..+3], so the old divergent
//         random s2 gather phase is deleted). e = leakyrelu(s1i+s2) computed
//         in registers; (e, j) compacted into per-wave LDS segment via
//         ballot; running wave max folded in.
// gather: p = exp(e-m) computed INLINE (old separate exp pass deleted);
//         lsum accumulated in the same loop (/32 for half-wave redundancy);
//         half-wave per pair, bf16 rows, 4-deep unroll.
__global__ __launch_bounds__(256, 4) void gat_row_kernel(
    const float* __restrict__ adj, const unsigned int* __restrict__ Whb,
    const float* __restrict__ s1, const float* __restrict__ s2,
    const float* __restrict__ S, float* __restrict__ out) {
  const int i = blockIdx.x;
  const int t = threadIdx.x;
  const int lane = t & 63;
  const int wave = t >> 6;
  __shared__ float2 pairs[4 * SEG];  // .x = e ; .y = j (int bits)
  __shared__ int counts[4];
  __shared__ float red[4];           // per-wave max
  __shared__ float red2[4];          // per-wave exp-sum
  __shared__ float fpart[4][FDIM];

  const float s1i = s1[i];
  const float4* __restrict__ arow = (const float4*)(adj + (size_t)i * N_NODES);
  const float4* __restrict__ srow = (const float4*)s2;
  float2* __restrict__ mypairs = pairs + wave * SEG;

  // ---- scan: adj + s2 chunks in flight, e in registers, ballot compact ----
  float4 av[8], sv[8];
#pragma unroll
  for (int it = 0; it < 8; ++it) av[it] = ntload4(&arow[it * 256 + t]);
#pragma unroll
  for (int it = 0; it < 8; ++it) sv[it] = srow[it * 256 + t];
  int cbase = 0;
  float lmax = -1e30f;
#pragma unroll
  for (int it = 0; it < 8; ++it) {
    const int j4 = it * 256 + t;
    float vv[4] = {av[it].x, av[it].y, av[it].z, av[it].w};
    float ss[4] = {sv[it].x, sv[it].y, sv[it].z, sv[it].w};
#pragma unroll
    for (int c = 0; c < 4; ++c) {
      bool pred = (vv[c] != 0.f);
      float e = s1i + ss[c];
      e = e > 0.f ? e : NEG_SLOPE * e;
      unsigned long long b = __ballot(pred);
      if (pred) {
        int pos = cbase + mbcnt64(b);
        if (pos < SEG) {
          float2 pr;
          pr.x = e;
          ((int*)&pr)[1] = j4 * 4 + c;
          mypairs[pos] = pr;
        }
      }
      lmax = fmaxf(lmax, pred ? e : -1e30f);
      cbase += (int)__popcll(b);
    }
  }
  const int mycnt = cbase < SEG ? cbase : SEG;
  if (lane == 0) counts[wave] = mycnt;
  for (int off = 32; off; off >>= 1) lmax = fmaxf(lmax, __shfl_down(lmax, off));
  if (lane == 0) red[wave] = lmax;
  __syncthreads();
  const int cnt = counts[0] + counts[1] + counts[2] + counts[3];
  float m = fmaxf(fmaxf(red[0], red[1]), fmaxf(red[2], red[3]));
  if (cnt < N_NODES) m = fmaxf(m, 0.f);  // adj==0 entries contribute z=0
  const float em = __expf(-m);

  // ---- gather: exp fused, half-wave per pair, bf16 rows, 4-deep unroll ----
  const int half = lane >> 5, lq = lane & 31;
  const uint2* __restrict__ Whb2 = (const uint2*)Whb;  // 32 x uint2 per row
  float ax = 0.f, ay = 0.f, az = 0.f, aw = 0.f, lsum = 0.f;
  const int nit = (mycnt + 1) >> 1;
  int it = 0;
  for (; it + 3 < nit; it += 4) {
#pragma unroll
    for (int c = 0; c < 4; ++c) {
      int p = 2 * (it + c) + half;
      bool ok = p < mycnt;
      float2 pr = mypairs[ok ? p : 0];
      int j = ((const int*)&pr)[1];
      uint2 d = Whb2[((size_t)j << 5) + lq];
      float pv = __expf(pr.x - m);
      float w = ok ? pv - em : 0.f;
      lsum += ok ? pv : 0.f;
      ax += w * __uint_as_float(d.x << 16);
      ay += w * __uint_as_float(d.x & 0xffff0000u);
      az += w * __uint_as_float(d.y << 16);
      aw += w * __uint_as_float(d.y & 0xffff0000u);
    }
  }
  for (; it < nit; ++it) {
    int p = 2 * it + half;
    bool ok = p < mycnt;
    float2 pr = mypairs[ok ? p : 0];
    int j = ((const int*)&pr)[1];
    uint2 d = Whb2[((size_t)j << 5) + lq];
    float pv = __expf(pr.x - m);
    float w = ok ? pv - em : 0.f;
    lsum += ok ? pv : 0.f;
    ax += w * __uint_as_float(d.x << 16);
    ay += w * __uint_as_float(d.x & 0xffff0000u);
    az += w * __uint_as_float(d.y << 16);
    aw += w * __uint_as_float(d.y & 0xffff0000u);
  }
  // reduce: each pair was handled by 32 lanes -> lsum is 32x over-counted
  for (int off = 32; off; off >>= 1) lsum += __shfl_down(lsum, off);
  if (lane == 0) red2[wave] = lsum * (1.f / 32.f);
  // combine odd/even halves (same features, disjoint neighbor subsets)
  ax += __shfl_down(ax, 32);
  ay += __shfl_down(ay, 32);
  az += __shfl_down(az, 32);
  aw += __shfl_down(aw, 32);
  if (lane < 32)
    *(float4*)&fpart[wave][4 * lq] = make_float4(ax, ay, az, aw);
  __syncthreads();
  if (t < FDIM) {
    float l = red2[0] + red2[1] + red2[2] + red2[3]
              + (float)(N_NODES - cnt) * em;
    float o = (fpart[0][t] + fpart[1][t] + fpart[2][t] + fpart[3][t]
               + em * S[t]) / l;
    out[(size_t)i * FDIM + t] = o;
  }
}

extern "C" void kernel_launch(void* const* d_in, const int* in_sizes, int n_in,
                              void* d_out, int out_size, void* d_ws, size_t ws_size,
                              hipStream_t stream) {
  const float* h   = (const float*)d_in[0];
  const float* adj = (const float*)d_in[1];
  const float* W   = (const float*)d_in[2];
  const float* a   = (const float*)d_in[3];
  float* out = (float*)d_out;
  // workspace: Whb(bf16, N*64 uints = 2 MB) | s1[N] | s2[N] | S[F] | WtG[F*F]
  unsigned int* Whb = (unsigned int*)d_ws;
  float* s1  = (float*)(Whb + (size_t)N_NODES * 64);
  float* s2  = s1 + N_NODES;
  float* S   = s2 + N_NODES;
  float* WtG = S + FDIM;

  hipMemsetAsync(S, 0, FDIM * sizeof(float), stream);
  hipLaunchKernelGGL(transpose_w_kernel, dim3(FDIM * FDIM / 256), dim3(256), 0,
                     stream, W, WtG);
  hipLaunchKernelGGL(wh_fused_kernel, dim3(N_NODES / 32), dim3(256), 0, stream,
                     h, WtG, a, Whb, s1, s2, S);
  hipLaunchKernelGGL(gat_row_kernel, dim3(N_NODES), dim3(256), 0, stream,
                     adj, Whb, s1, s2, S, out);
}